// Round 3
// baseline (4845.905 us; speedup 1.0000x reference)
//
#include <hip/hip_runtime.h>
#include <stdint.h>

// ---------------------------------------------------------------------------
// RNNClassifier pipeline for MI355X (gfx950). Dtype-agnostic: a sniffer
// kernel detects whether float inputs are f32 or bf16, a converter kernel
// normalizes everything to bf16 in ws, and the epilogue writes d_out in the
// matching dtype. Core pipeline (bf16 MFMA, f32 accum):
//  k_prep : swizzle conv/w_ih/w_hh weights into MFMA B-fragment order
//  k_conv : embedding gather + (conv3|conv5) as one K=640 im2col GEMM -> y
//           + fused BN batch-stat partial sums (f32 atomics)
//  k_bn   : finalize BN scale/shift
//  k_gx   : gx = ReLU(BN(y)) @ w_ih^T + b_ih + b_hh, swizzled to C-layout
//  k_lstm : persistent 16 blocks x 16 batch rows x 8 waves; h via
//           double-buffered LDS frag buffer; w_hh kt0..3 in regs, kt4..7 L2
//  k_attn : attn/attn_out/logits epilogue
//
// MFMA 16x16x32 bf16 layouts (guide m89/m120):
//   A: lane holds A[m=lane&15][k=kt*32+(lane>>4)*8+j], j=0..7
//   B: lane holds B[k=kt*32+(lane>>4)*8+j][n=lane&15]
//   C/D: lane holds D[m=(lane>>4)*4+r][n=lane&15], r=0..3
//
// R2 fix: k_conv staged only 8/16 int4 segments per embedding row -> upper
// 64 channels of every LDS row were uninitialized (round-1 NaN / round-2
// finite-wrong). Now stages all 16.
// ---------------------------------------------------------------------------

typedef __bf16 bf16x8 __attribute__((ext_vector_type(8)));
typedef float  f32x4  __attribute__((ext_vector_type(4)));

__device__ __forceinline__ float bf2f(uint16_t h){
  union { uint32_t u; float f; } v; v.u = ((uint32_t)h) << 16; return v.f;
}
__device__ __forceinline__ uint16_t f2bf(float f){
  union { float f; uint32_t u; } v; v.f = f;
  return (uint16_t)((v.u + 0x7FFFu + ((v.u >> 16) & 1u)) >> 16);
}
__device__ __forceinline__ bf16x8 ld_frag(const uint16_t* p){
  union { int4 i; bf16x8 b; } u; u.i = *(const int4*)p; return u.b;
}
__device__ __forceinline__ f32x4 mfma16(bf16x8 a, bf16x8 b, f32x4 c){
  return __builtin_amdgcn_mfma_f32_16x16x32_bf16(a, b, c, 0, 0, 0);
}
__device__ __forceinline__ float sigm(float x){
  return __builtin_amdgcn_rcpf(1.f + __expf(-x));
}
__device__ __forceinline__ float tanh_(float x){
  return 2.f * __builtin_amdgcn_rcpf(1.f + __expf(-2.f * x)) - 1.f;
}

// ---------------------------------------------------------------------------
// k_sniff: classify float-input dtype. bf16 data: exponent byte of the low
// half of each u32 lands in [0x60,0x7E] for ~all of 0.05*N(0,1); f32 data:
// those bits are mid-mantissa (uniform) -> ~12% hit rate. flag=1 means bf16.
// ---------------------------------------------------------------------------
__global__ __launch_bounds__(256) void k_sniff(const uint32_t* __restrict__ e,
                                               int* __restrict__ flag)
{
  __shared__ int cnt;
  int tid = threadIdx.x;
  if (tid == 0) cnt = 0;
  __syncthreads();
  uint32_t u = e[tid];
  uint32_t ex = (u >> 7) & 0xFFu;
  if (ex >= 0x60u && ex <= 0x7Eu) atomicAdd(&cnt, 1);
  __syncthreads();
  if (tid == 0) flag[0] = (cnt >= 192) ? 1 : 0;
}

// ---------------------------------------------------------------------------
// k_cvt: normalize 13 float tensors to bf16 ws buffers. 4096 elems/block.
// ---------------------------------------------------------------------------
struct CvtDesc { const void* s; uint16_t* d; int n; int c0; };
struct CvtArgs { CvtDesc a[13]; };

__global__ __launch_bounds__(256) void k_cvt(CvtArgs A, const int* __restrict__ flag)
{
  int ch = blockIdx.x;
  int i = 0;
  #pragma unroll
  for (int k = 1; k < 13; ++k) if (ch >= A.a[k].c0) i = k;
  const void* s = A.a[i].s;
  uint16_t*   d = A.a[i].d;
  int n = A.a[i].n;
  int base = (ch - A.a[i].c0) * 4096 + threadIdx.x;
  int isb = *flag;
  #pragma unroll 4
  for (int r = 0; r < 16; ++r) {
    int idx = base + r * 256;
    if (idx < n)
      d[idx] = isb ? ((const uint16_t*)s)[idx] : f2bf(((const float*)s)[idx]);
  }
}

// ---------------------------------------------------------------------------
// k_prep: weight swizzles + zeroing (ws is poisoned 0xAA before every call)
// fragC: [kt=0..19][nt=0..15][lane][8]  unified conv B, K=640 (delta=kt>>2)
// fragI/fragH: [tile=nt*8+kt][lane][8] for w_ih / w_hh
// ---------------------------------------------------------------------------
__global__ __launch_bounds__(256) void k_prep(
    const uint16_t* __restrict__ c1w, const uint16_t* __restrict__ c2w,
    const uint16_t* __restrict__ wih, const uint16_t* __restrict__ whh,
    uint16_t* __restrict__ fragC, uint16_t* __restrict__ fragI,
    uint16_t* __restrict__ fragH, float* __restrict__ bnbuf,
    uint16_t* __restrict__ wsH, float* __restrict__ wsC)
{
  int g = blockIdx.x * 256 + threadIdx.x;
  if (g < 20480) {                       // conv B fragments (320 tiles)
    int tile = g >> 6, lane = g & 63;
    int kt = tile >> 4, nt = tile & 15;
    int q = lane >> 4, c16 = lane & 15;
    int dlt = kt >> 2;                   // time offset delta = dlt - 2
    int o = nt * 16 + c16;
    union { int4 i; uint16_t u[8]; } v;
    #pragma unroll
    for (int j = 0; j < 8; ++j) {
      int i = (kt & 3) * 32 + q * 8 + j;
      uint16_t val = 0;
      if (o < 128) { int k = dlt - 1; if (k >= 0 && k < 3) val = c1w[(o*128 + i)*3 + k]; }
      else         { int k = dlt;     if (k < 5)           val = c2w[((o-128)*128 + i)*5 + k]; }
      v.u[j] = val;
    }
    *(int4*)(fragC + tile * 512 + lane * 8) = v.i;
  } else if (g < 53248) {                // w_ih fragments (512 tiles)
    int gg = g - 20480;
    int tile = gg >> 6, lane = gg & 63;
    int nt = tile >> 3, kt = tile & 7;
    int q = lane >> 4, c16 = lane & 15;
    *(int4*)(fragI + tile * 512 + lane * 8) =
        *(const int4*)(wih + (nt*16 + c16)*256 + kt*32 + q*8);
  } else if (g < 86016) {                // w_hh fragments (512 tiles)
    int gg = g - 53248;
    int tile = gg >> 6, lane = gg & 63;
    int nt = tile >> 3, kt = tile & 7;
    int q = lane >> 4, c16 = lane & 15;
    *(int4*)(fragH + tile * 512 + lane * 8) =
        *(const int4*)(whh + (nt*16 + c16)*256 + kt*32 + q*8);
  } else if (g < 94208) {                // zero wsH (h carry, 65536 bf16)
    ((int4*)wsH)[g - 86016] = make_int4(0,0,0,0);
  } else if (g < 110592) {               // zero wsC (c carry, 65536 f32)
    ((int4*)wsC)[g - 94208] = make_int4(0,0,0,0);
  } else if (g < 110720) {               // zero bn sums (512 f32)
    ((int4*)bnbuf)[g - 110592] = make_int4(0,0,0,0);
  }
}

// ---------------------------------------------------------------------------
// k_conv: per block = one (b, 64-t tile). Stage 68 padded embedding rows in
// LDS (stride 136), then one K=640 MFMA GEMM. Wave w owns nt [4w,4w+4).
// ---------------------------------------------------------------------------
__global__ __launch_bounds__(256) void k_conv(
    const int* __restrict__ x, const uint16_t* __restrict__ etab,
    const uint16_t* __restrict__ fragC,
    const uint16_t* __restrict__ c1b, const uint16_t* __restrict__ c2b,
    uint16_t* __restrict__ y, float* __restrict__ bnbuf)
{
  __shared__ __align__(16) uint16_t embS[68 * 136];
  int blk = blockIdx.x;
  int b = blk >> 3, t0 = (blk & 7) * 64;
  int tid = threadIdx.x;
  int lane = tid & 63, w = tid >> 6;
  int q = lane >> 4, c16 = lane & 15;

  for (int s = tid; s < 1088; s += 256) {      // 68 rows x 16 segs of 16B
    int r = s >> 4, seg = s & 15;
    int t = t0 - 2 + r;
    int4 val = make_int4(0,0,0,0);
    if (t >= 0 && t < 512) {
      int idx = x[b*512 + t];
      val = *(const int4*)(etab + (size_t)idx*128 + seg*8);
    }
    *(int4*)(embS + r*136 + seg*8) = val;
  }
  __syncthreads();

  f32x4 acc[4][4];                              // [ntl][Mt]
  #pragma unroll
  for (int i = 0; i < 4; ++i)
    #pragma unroll
    for (int j = 0; j < 4; ++j) acc[i][j] = (f32x4){0.f,0.f,0.f,0.f};

  #pragma unroll 4
  for (int kt = 0; kt < 20; ++kt) {
    int dlt = kt >> 2;
    int i0 = (kt & 3)*32 + q*8;
    bf16x8 a[4];
    #pragma unroll
    for (int Mt = 0; Mt < 4; ++Mt)
      a[Mt] = ld_frag(embS + (Mt*16 + c16 + dlt)*136 + i0);
    #pragma unroll
    for (int ntl = 0; ntl < 4; ++ntl) {
      int nt = w*4 + ntl;
      bf16x8 bf = ld_frag(fragC + (kt*16 + nt)*512 + lane*8);
      #pragma unroll
      for (int Mt = 0; Mt < 4; ++Mt)
        acc[ntl][Mt] = mfma16(a[Mt], bf, acc[ntl][Mt]);
    }
  }

  #pragma unroll
  for (int ntl = 0; ntl < 4; ++ntl) {
    int ch = (w*4 + ntl)*16 + c16;
    float bias = bf2f(ch < 128 ? c1b[ch] : c2b[ch - 128]);
    float s0 = 0.f, s1 = 0.f;
    #pragma unroll
    for (int Mt = 0; Mt < 4; ++Mt) {
      #pragma unroll
      for (int r = 0; r < 4; ++r) {
        float v = acc[ntl][Mt][r] + bias;
        int t = t0 + Mt*16 + q*4 + r;
        y[((size_t)b*512 + t)*256 + ch] = f2bf(v);
        s0 += v; s1 += v*v;
      }
    }
    s0 += __shfl_xor(s0, 16); s0 += __shfl_xor(s0, 32);
    s1 += __shfl_xor(s1, 16); s1 += __shfl_xor(s1, 32);
    if (q == 0) { atomicAdd(&bnbuf[ch], s0); atomicAdd(&bnbuf[256 + ch], s1); }
  }
}

// ---------------------------------------------------------------------------
__global__ void k_bn(const uint16_t* __restrict__ gamma,
                     const uint16_t* __restrict__ beta,
                     float* __restrict__ bnbuf)
{
  int c = threadIdx.x;                 // 256
  const float inv = 1.f / 131072.f;
  float mean = bnbuf[c] * inv;
  float var  = fmaxf(bnbuf[256 + c] * inv - mean*mean, 0.f);
  float sc   = bf2f(gamma[c]) * rsqrtf(var + 1e-5f);
  bnbuf[512 + c] = sc;
  bnbuf[768 + c] = bf2f(beta[c]) - mean * sc;
}

// ---------------------------------------------------------------------------
// k_gx: gate-x for one T-chunk of 128 steps. Output slab per (t_local,bg):
// [nt 0..63][lane][4 r-values] bf16 = the LSTM's read pattern.
// grid = (512, 4): x = tl*4 + bquad, y = N-block of 256 gate cols.
// ---------------------------------------------------------------------------
__global__ __launch_bounds__(256) void k_gx(
    const uint16_t* __restrict__ y, const float* __restrict__ bnbuf,
    const uint16_t* __restrict__ fragI, const uint16_t* __restrict__ bih,
    const uint16_t* __restrict__ bhh, uint16_t* __restrict__ gx, int tbase)
{
  __shared__ __align__(16) uint16_t aS[16384];   // A staged in frag order
  int Mblk = blockIdx.x, Nblk = blockIdx.y;
  int tl = Mblk >> 2;
  int b0 = (Mblk & 3) * 64;
  int t = tbase + tl;
  int tid = threadIdx.x, lane = tid & 63, w = tid >> 6;
  int q = lane >> 4, c16 = lane & 15;

  for (int s = tid; s < 2048; s += 256) {        // 64 rows x 32 segs(8ch)
    int row = s >> 5, seg = s & 31;
    union { int4 i; uint16_t u[8]; } vv, oo;
    vv.i = *(const int4*)(y + ((size_t)(b0 + row)*512 + t)*256 + seg*8);
    #pragma unroll
    for (int j = 0; j < 8; ++j) {
      int ch = seg*8 + j;
      float f = bf2f(vv.u[j]) * bnbuf[512 + ch] + bnbuf[768 + ch];
      oo.u[j] = f2bf(fmaxf(f, 0.f));
    }
    int Mt = row >> 4, mL = row & 15, kt2 = seg >> 2, qq = seg & 3;
    *(int4*)(aS + ((Mt*8 + kt2)*64 + qq*16 + mL)*8) = oo.i;
  }
  __syncthreads();

  f32x4 acc[4][4];                               // [ntl][Mt]
  #pragma unroll
  for (int ntl = 0; ntl < 4; ++ntl) {
    int n = (Nblk*16 + w*4 + ntl)*16 + c16;
    float bias = bf2f(bih[n]) + bf2f(bhh[n]);
    #pragma unroll
    for (int Mt = 0; Mt < 4; ++Mt) acc[ntl][Mt] = (f32x4){bias,bias,bias,bias};
  }
  #pragma unroll
  for (int kt = 0; kt < 8; ++kt) {
    bf16x8 a[4];
    #pragma unroll
    for (int Mt = 0; Mt < 4; ++Mt)
      a[Mt] = ld_frag(aS + ((Mt*8 + kt)*64 + lane)*8);
    #pragma unroll
    for (int ntl = 0; ntl < 4; ++ntl) {
      int nt = Nblk*16 + w*4 + ntl;
      bf16x8 bf = ld_frag(fragI + ((size_t)(nt*8 + kt))*512 + lane*8);
      #pragma unroll
      for (int Mt = 0; Mt < 4; ++Mt)
        acc[ntl][Mt] = mfma16(a[Mt], bf, acc[ntl][Mt]);
    }
  }
  #pragma unroll
  for (int ntl = 0; ntl < 4; ++ntl) {
    int nt = Nblk*16 + w*4 + ntl;
    #pragma unroll
    for (int Mt = 0; Mt < 4; ++Mt) {
      int bg = (Mblk & 3)*4 + Mt;
      uint32_t lo = (uint32_t)f2bf(acc[ntl][Mt][0]) | ((uint32_t)f2bf(acc[ntl][Mt][1]) << 16);
      uint32_t hi = (uint32_t)f2bf(acc[ntl][Mt][2]) | ((uint32_t)f2bf(acc[ntl][Mt][3]) << 16);
      uint2 vv = {lo, hi};
      *(uint2*)(gx + ((size_t)(tl*16 + bg))*16384 + nt*256 + lane*4) = vv;
    }
  }
}

// ---------------------------------------------------------------------------
// k_lstm: 16 blocks x 512 threads. Block bg owns batch rows [16bg,16bg+16).
// Wave w owns units [32w,32w+32): gate tiles ntg = {2w+p, 16+2w+p, 32+..,
// 48+..}. h round-trips through double-buffered LDS frag buffer.
// ---------------------------------------------------------------------------
__device__ __forceinline__ float gxf(uint2 v, int r){
  uint32_t d = (r < 2) ? v.x : v.y;
  return bf2f((r & 1) ? (uint16_t)(d >> 16) : (uint16_t)(d & 0xffffu));
}

__global__ __launch_bounds__(512, 2) void k_lstm(
    const uint16_t* __restrict__ gx, const uint16_t* __restrict__ fragH,
    const int* __restrict__ lengths, uint16_t* __restrict__ wsH,
    float* __restrict__ wsC, float* __restrict__ hn,
    int tbase, int tcount, int last)
{
  __shared__ __align__(16) uint16_t aS[2 * 4096];
  int bg = blockIdx.x;
  int tid = threadIdx.x, lane = tid & 63, w = tid >> 6;
  int q = lane >> 4, c16 = lane & 15;

  ((int4*)aS)[tid] = ((const int4*)(wsH + bg*4096))[tid];  // h carry -> buf0

  int li[4];
  #pragma unroll
  for (int r = 0; r < 4; ++r) li[r] = lengths[bg*16 + q*4 + r];
  int Tmax = lengths[bg*16];                   // lengths sorted descending

  float cr[2][4], hr[2][4];
  #pragma unroll
  for (int p = 0; p < 2; ++p)
    #pragma unroll
    for (int r = 0; r < 4; ++r)
      cr[p][r] = wsC[(bg*16 + q*4 + r)*256 + w*32 + p*16 + c16];

  int ntg[8];
  bf16x8 breg[8][4];                           // w_hh kt0..3 resident
  #pragma unroll
  for (int gp = 0; gp < 8; ++gp) {
    ntg[gp] = (gp >> 1)*16 + 2*w + (gp & 1);
    #pragma unroll
    for (int kt = 0; kt < 4; ++kt)
      breg[gp][kt] = ld_frag(fragH + (ntg[gp]*8 + kt)*512 + lane*8);
  }
  __syncthreads();

  #pragma unroll
  for (int p = 0; p < 2; ++p)
    #pragma unroll
    for (int r = 0; r < 4; ++r) {
      int lA = (q*4 + r) + 16*(2*p + (c16 >> 3));
      hr[p][r] = bf2f(aS[w*512 + lA*8 + (c16 & 7)]);
    }

  int cur = 0;
  int tEnd = min(tbase + tcount, Tmax);
  for (int t = tbase; t < tEnd; ++t) {
    const uint16_t* Ar = aS + cur*4096;
    uint16_t* Aw = aS + (cur ^ 1)*4096;
    const uint16_t* gxs = gx + ((size_t)((t - tbase)*16 + bg))*16384;

    uint2 gxr[8];
    #pragma unroll
    for (int gp = 0; gp < 8; ++gp)
      gxr[gp] = *(const uint2*)(gxs + ntg[gp]*256 + lane*4);

    f32x4 acc[8];
    #pragma unroll
    for (int gp = 0; gp < 8; ++gp) acc[gp] = (f32x4){0.f,0.f,0.f,0.f};

    #pragma unroll
    for (int kt = 0; kt < 8; ++kt) {
      bf16x8 a = ld_frag(Ar + kt*512 + lane*8);
      if (kt < 4) {
        #pragma unroll
        for (int gp = 0; gp < 8; ++gp)
          acc[gp] = mfma16(a, breg[gp][kt], acc[gp]);
      } else {
        bf16x8 bb[8];                          // kt4..7 streamed from L2
        #pragma unroll
        for (int gp = 0; gp < 8; ++gp)
          bb[gp] = ld_frag(fragH + (ntg[gp]*8 + kt)*512 + lane*8);
        #pragma unroll
        for (int gp = 0; gp < 8; ++gp)
          acc[gp] = mfma16(a, bb[gp], acc[gp]);
      }
    }

    #pragma unroll
    for (int p = 0; p < 2; ++p) {
      #pragma unroll
      for (int r = 0; r < 4; ++r) {
        float gi = acc[0 + p][r] + gxf(gxr[0 + p], r);
        float gf = acc[2 + p][r] + gxf(gxr[2 + p], r);
        float gg = acc[4 + p][r] + gxf(gxr[4 + p], r);
        float go = acc[6 + p][r] + gxf(gxr[6 + p], r);
        float cn = sigm(gf)*cr[p][r] + sigm(gi)*tanh_(gg);
        float hw = sigm(go)*tanh_(cn);
        bool upd = (t < li[r]);
        cn = upd ? cn : cr[p][r];
        hw = upd ? hw : hr[p][r];
        cr[p][r] = cn; hr[p][r] = hw;
        int lA = (q*4 + r) + 16*(2*p + (c16 >> 3));
        Aw[w*512 + lA*8 + (c16 & 7)] = f2bf(hw);   // always write (dbuf)
      }
    }
    __syncthreads();
    cur ^= 1;
  }

  ((int4*)(wsH + bg*4096))[tid] = ((const int4*)(aS + cur*4096))[tid];
  #pragma unroll
  for (int p = 0; p < 2; ++p)
    #pragma unroll
    for (int r = 0; r < 4; ++r)
      wsC[(bg*16 + q*4 + r)*256 + w*32 + p*16 + c16] = cr[p][r];

  if (last) {
    #pragma unroll
    for (int j = 0; j < 8; ++j)
      hn[(bg*16 + c16)*256 + w*32 + q*8 + j] =
          bf2f(aS[cur*4096 + w*512 + lane*8 + j]);
  }
}

// ---------------------------------------------------------------------------
// k_attn: one block per batch row. out = [logits 256x31][attn_out 256x256],
// dtype selected by flag (1 = bf16, 0 = f32).
// ---------------------------------------------------------------------------
__global__ __launch_bounds__(256) void k_attn(
    const uint16_t* __restrict__ y, const float* __restrict__ hn,
    const uint16_t* __restrict__ linw, const uint16_t* __restrict__ linb,
    void* __restrict__ outv, const int* __restrict__ flag)
{
  __shared__ float hnS[256];
  __shared__ float attnS[512];
  int b = blockIdx.x;
  int tid = threadIdx.x, lane = tid & 63, w = tid >> 6;
  int isb = *flag;
  hnS[tid] = hn[b*256 + tid];
  __syncthreads();
  for (int t = w; t < 512; t += 4) {
    uint2 d = *(const uint2*)(y + ((size_t)b*512 + t)*256 + lane*4);
    float s = bf2f((uint16_t)(d.x & 0xffffu)) * hnS[lane*4 + 0]
            + bf2f((uint16_t)(d.x >> 16))     * hnS[lane*4 + 1]
            + bf2f((uint16_t)(d.y & 0xffffu)) * hnS[lane*4 + 2]
            + bf2f((uint16_t)(d.y >> 16))     * hnS[lane*4 + 3];
    #pragma unroll
    for (int off = 32; off >= 1; off >>= 1) s += __shfl_xor(s, off);
    if (lane == 0) attnS[t] = s * 0.0625f;     // 1/sqrt(256)
  }
  __syncthreads();
  float acc = 0.f;
  #pragma unroll 4
  for (int t = 0; t < 512; ++t)
    acc += attnS[t] * bf2f(y[((size_t)b*512 + t)*256 + tid]);
  if (isb) ((uint16_t*)outv)[7936 + b*256 + tid] = f2bf(acc);
  else     ((float*)outv)[7936 + b*256 + tid] = acc;
  if (tid < 31) {
    float a2 = bf2f(linb[tid]);
    for (int k = 0; k < 256; ++k) a2 += hnS[k] * bf2f(linw[tid*256 + k]);
    if (isb) ((uint16_t*)outv)[b*31 + tid] = f2bf(a2);
    else     ((float*)outv)[b*31 + tid] = a2;
  }
}

// ---------------------------------------------------------------------------
extern "C" void kernel_launch(void* const* d_in, const int* in_sizes, int n_in,
                              void* d_out, int out_size, void* d_ws, size_t ws_size,
                              hipStream_t stream)
{
  (void)in_sizes; (void)out_size;
  if (n_in < 15) return;
  const int* x   = (const int*)d_in[0];
  const int* len = (const int*)d_in[1];

  uint8_t* p = (uint8_t*)d_ws;
  auto take = [&](size_t n){ uint8_t* r = p; p += (n + 255) & ~(size_t)255; return r; };
  int*      flag  = (int*)take(256);
  uint16_t* c1bC  = (uint16_t*)take(256);
  uint16_t* c2bC  = (uint16_t*)take(256);
  uint16_t* bngC  = (uint16_t*)take(512);
  uint16_t* bnbC  = (uint16_t*)take(512);
  uint16_t* bihC  = (uint16_t*)take(2048);
  uint16_t* bhhC  = (uint16_t*)take(2048);
  uint16_t* linwC = (uint16_t*)take(15872);
  uint16_t* linbC = (uint16_t*)take(64);
  uint16_t* fragC = (uint16_t*)take(327680);
  uint16_t* fragI = (uint16_t*)take(524288);
  uint16_t* fragH = (uint16_t*)take(524288);
  float*    bnbuf = (float*)take(4096);            // sum|sq|scale|shift x256
  uint16_t* wsH   = (uint16_t*)take(131072);       // h carry (frag layout)
  float*    wsC   = (float*)take(262144);          // c carry
  float*    hnbuf = (float*)take(262144);          // final h
  uint16_t* y     = (uint16_t*)take(67108864ull);  // (b,t,c) bf16
  uint16_t* gxb   = (uint16_t*)take(67108864ull);  // gx chunk (128 steps)
  if ((size_t)(p - (uint8_t*)d_ws) > ws_size) return;

  // big converted tensors live inside gxb (dead before k_gx first writes it)
  uint16_t* etabC = gxb;                                    // 12.8 MB
  uint16_t* c1wC  = (uint16_t*)((uint8_t*)gxb + 16u*1024*1024);
  uint16_t* c2wC  = (uint16_t*)((uint8_t*)gxb + 17u*1024*1024);
  uint16_t* wihC  = (uint16_t*)((uint8_t*)gxb + 18u*1024*1024);
  uint16_t* whhC  = (uint16_t*)((uint8_t*)gxb + 19u*1024*1024);

  k_sniff<<<1, 256, 0, stream>>>((const uint32_t*)d_in[2], flag);

  CvtArgs A;
  int c0 = 0;
  auto put = [&](int i, const void* s, uint16_t* d, int n){
    A.a[i].s = s; A.a[i].d = d; A.a[i].n = n; A.a[i].c0 = c0;
    c0 += (n + 4095) / 4096;
  };
  put(0,  d_in[2],  etabC, 6400000);
  put(1,  d_in[3],  c1wC,  49152);
  put(2,  d_in[4],  c1bC,  128);
  put(3,  d_in[5],  c2wC,  81920);
  put(4,  d_in[6],  c2bC,  128);
  put(5,  d_in[7],  bngC,  256);
  put(6,  d_in[8],  bnbC,  256);
  put(7,  d_in[9],  wihC,  262144);
  put(8,  d_in[10], whhC,  262144);
  put(9,  d_in[11], bihC,  1024);
  put(10, d_in[12], bhhC,  1024);
  put(11, d_in[13], linwC, 7936);
  put(12, d_in[14], linbC, 31);
  k_cvt<<<c0, 256, 0, stream>>>(A, flag);

  k_prep<<<512, 256, 0, stream>>>(c1wC, c2wC, wihC, whhC, fragC, fragI, fragH,
                                  bnbuf, wsH, wsC);
  k_conv<<<2048, 256, 0, stream>>>(x, etabC, fragC, c1bC, c2bC, y, bnbuf);
  k_bn<<<1, 256, 0, stream>>>(bngC, bnbC, bnbuf);
  for (int c = 0; c < 4; ++c) {
    k_gx<<<dim3(512, 4), 256, 0, stream>>>(y, bnbuf, fragI, bihC, bhhC, gxb, c*128);
    k_lstm<<<16, 512, 0, stream>>>(gxb, fragH, len, wsH, wsC, hnbuf,
                                   c*128, 128, (c == 3) ? 1 : 0);
  }
  k_attn<<<256, 256, 0, stream>>>(y, hnbuf, linwC, linbC, d_out, flag);
}

// Round 4
// 4083.717 us; speedup vs baseline: 1.1866x; 1.1866x over previous
//
#include <hip/hip_runtime.h>
#include <stdint.h>

// ---------------------------------------------------------------------------
// RNNClassifier pipeline for MI355X (gfx950). Dtype-agnostic: a sniffer
// kernel detects whether float inputs are f32 or bf16, a converter kernel
// normalizes everything to bf16 in ws, and the epilogue writes d_out in the
// matching dtype. Core pipeline (bf16 MFMA, f32 accum):
//  k_prep : swizzle conv/w_ih/w_hh weights into MFMA B-fragment order
//  k_conv : embedding gather + (conv3|conv5) as one K=640 im2col GEMM -> y
//  k_bn   : finalize BN scale/shift
//  k_gx   : gx = ReLU(BN(y)) @ w_ih^T + b_ih + b_hh, swizzled to C-layout
//  k_lstm : v2 (R4): persistent 16 blocks x 8 waves; software-pipelined gx
//           prefetch (t+1 loaded during t), acc initialized from gx,
//           w_hh kt0..3 register-resident, kt4..7 streamed from L2 with
//           +1-group lookahead so the L2 port never idles.
//  k_attn : attn/attn_out/logits epilogue
//
// MFMA 16x16x32 bf16 layouts (guide m89/m120):
//   A: lane holds A[m=lane&15][k=kt*32+(lane>>4)*8+j], j=0..7
//   B: lane holds B[k=kt*32+(lane>>4)*8+j][n=lane&15]
//   C/D: lane holds D[m=(lane>>4)*4+r][n=lane&15], r=0..3
// ---------------------------------------------------------------------------

typedef __bf16 bf16x8 __attribute__((ext_vector_type(8)));
typedef float  f32x4  __attribute__((ext_vector_type(4)));

__device__ __forceinline__ float bf2f(uint16_t h){
  union { uint32_t u; float f; } v; v.u = ((uint32_t)h) << 16; return v.f;
}
__device__ __forceinline__ uint16_t f2bf(float f){
  union { float f; uint32_t u; } v; v.f = f;
  return (uint16_t)((v.u + 0x7FFFu + ((v.u >> 16) & 1u)) >> 16);
}
__device__ __forceinline__ bf16x8 ld_frag(const uint16_t* p){
  union { int4 i; bf16x8 b; } u; u.i = *(const int4*)p; return u.b;
}
__device__ __forceinline__ f32x4 mfma16(bf16x8 a, bf16x8 b, f32x4 c){
  return __builtin_amdgcn_mfma_f32_16x16x32_bf16(a, b, c, 0, 0, 0);
}
__device__ __forceinline__ float sigm(float x){
  return __builtin_amdgcn_rcpf(1.f + __expf(-x));
}
__device__ __forceinline__ float tanh_(float x){
  return 2.f * __builtin_amdgcn_rcpf(1.f + __expf(-2.f * x)) - 1.f;
}

// ---------------------------------------------------------------------------
__global__ __launch_bounds__(256) void k_sniff(const uint32_t* __restrict__ e,
                                               int* __restrict__ flag)
{
  __shared__ int cnt;
  int tid = threadIdx.x;
  if (tid == 0) cnt = 0;
  __syncthreads();
  uint32_t u = e[tid];
  uint32_t ex = (u >> 7) & 0xFFu;
  if (ex >= 0x60u && ex <= 0x7Eu) atomicAdd(&cnt, 1);
  __syncthreads();
  if (tid == 0) flag[0] = (cnt >= 192) ? 1 : 0;
}

// ---------------------------------------------------------------------------
struct CvtDesc { const void* s; uint16_t* d; int n; int c0; };
struct CvtArgs { CvtDesc a[13]; };

__global__ __launch_bounds__(256) void k_cvt(CvtArgs A, const int* __restrict__ flag)
{
  int ch = blockIdx.x;
  int i = 0;
  #pragma unroll
  for (int k = 1; k < 13; ++k) if (ch >= A.a[k].c0) i = k;
  const void* s = A.a[i].s;
  uint16_t*   d = A.a[i].d;
  int n = A.a[i].n;
  int base = (ch - A.a[i].c0) * 4096 + threadIdx.x;
  int isb = *flag;
  #pragma unroll 4
  for (int r = 0; r < 16; ++r) {
    int idx = base + r * 256;
    if (idx < n)
      d[idx] = isb ? ((const uint16_t*)s)[idx] : f2bf(((const float*)s)[idx]);
  }
}

// ---------------------------------------------------------------------------
__global__ __launch_bounds__(256) void k_prep(
    const uint16_t* __restrict__ c1w, const uint16_t* __restrict__ c2w,
    const uint16_t* __restrict__ wih, const uint16_t* __restrict__ whh,
    uint16_t* __restrict__ fragC, uint16_t* __restrict__ fragI,
    uint16_t* __restrict__ fragH, float* __restrict__ bnbuf,
    uint16_t* __restrict__ wsH, float* __restrict__ wsC)
{
  int g = blockIdx.x * 256 + threadIdx.x;
  if (g < 20480) {                       // conv B fragments (320 tiles)
    int tile = g >> 6, lane = g & 63;
    int kt = tile >> 4, nt = tile & 15;
    int q = lane >> 4, c16 = lane & 15;
    int dlt = kt >> 2;
    int o = nt * 16 + c16;
    union { int4 i; uint16_t u[8]; } v;
    #pragma unroll
    for (int j = 0; j < 8; ++j) {
      int i = (kt & 3) * 32 + q * 8 + j;
      uint16_t val = 0;
      if (o < 128) { int k = dlt - 1; if (k >= 0 && k < 3) val = c1w[(o*128 + i)*3 + k]; }
      else         { int k = dlt;     if (k < 5)           val = c2w[((o-128)*128 + i)*5 + k]; }
      v.u[j] = val;
    }
    *(int4*)(fragC + tile * 512 + lane * 8) = v.i;
  } else if (g < 53248) {                // w_ih fragments (512 tiles)
    int gg = g - 20480;
    int tile = gg >> 6, lane = gg & 63;
    int nt = tile >> 3, kt = tile & 7;
    int q = lane >> 4, c16 = lane & 15;
    *(int4*)(fragI + tile * 512 + lane * 8) =
        *(const int4*)(wih + (nt*16 + c16)*256 + kt*32 + q*8);
  } else if (g < 86016) {                // w_hh fragments (512 tiles)
    int gg = g - 53248;
    int tile = gg >> 6, lane = gg & 63;
    int nt = tile >> 3, kt = tile & 7;
    int q = lane >> 4, c16 = lane & 15;
    *(int4*)(fragH + tile * 512 + lane * 8) =
        *(const int4*)(whh + (nt*16 + c16)*256 + kt*32 + q*8);
  } else if (g < 94208) {                // zero wsH
    ((int4*)wsH)[g - 86016] = make_int4(0,0,0,0);
  } else if (g < 110592) {               // zero wsC
    ((int4*)wsC)[g - 94208] = make_int4(0,0,0,0);
  } else if (g < 110720) {               // zero bn sums
    ((int4*)bnbuf)[g - 110592] = make_int4(0,0,0,0);
  }
}

// ---------------------------------------------------------------------------
__global__ __launch_bounds__(256) void k_conv(
    const int* __restrict__ x, const uint16_t* __restrict__ etab,
    const uint16_t* __restrict__ fragC,
    const uint16_t* __restrict__ c1b, const uint16_t* __restrict__ c2b,
    uint16_t* __restrict__ y, float* __restrict__ bnbuf)
{
  __shared__ __align__(16) uint16_t embS[68 * 136];
  int blk = blockIdx.x;
  int b = blk >> 3, t0 = (blk & 7) * 64;
  int tid = threadIdx.x;
  int lane = tid & 63, w = tid >> 6;
  int q = lane >> 4, c16 = lane & 15;

  for (int s = tid; s < 1088; s += 256) {      // 68 rows x 16 segs of 16B
    int r = s >> 4, seg = s & 15;
    int t = t0 - 2 + r;
    int4 val = make_int4(0,0,0,0);
    if (t >= 0 && t < 512) {
      int idx = x[b*512 + t];
      val = *(const int4*)(etab + (size_t)idx*128 + seg*8);
    }
    *(int4*)(embS + r*136 + seg*8) = val;
  }
  __syncthreads();

  f32x4 acc[4][4];
  #pragma unroll
  for (int i = 0; i < 4; ++i)
    #pragma unroll
    for (int j = 0; j < 4; ++j) acc[i][j] = (f32x4){0.f,0.f,0.f,0.f};

  #pragma unroll 4
  for (int kt = 0; kt < 20; ++kt) {
    int dlt = kt >> 2;
    int i0 = (kt & 3)*32 + q*8;
    bf16x8 a[4];
    #pragma unroll
    for (int Mt = 0; Mt < 4; ++Mt)
      a[Mt] = ld_frag(embS + (Mt*16 + c16 + dlt)*136 + i0);
    #pragma unroll
    for (int ntl = 0; ntl < 4; ++ntl) {
      int nt = w*4 + ntl;
      bf16x8 bf = ld_frag(fragC + (kt*16 + nt)*512 + lane*8);
      #pragma unroll
      for (int Mt = 0; Mt < 4; ++Mt)
        acc[ntl][Mt] = mfma16(a[Mt], bf, acc[ntl][Mt]);
    }
  }

  #pragma unroll
  for (int ntl = 0; ntl < 4; ++ntl) {
    int ch = (w*4 + ntl)*16 + c16;
    float bias = bf2f(ch < 128 ? c1b[ch] : c2b[ch - 128]);
    float s0 = 0.f, s1 = 0.f;
    #pragma unroll
    for (int Mt = 0; Mt < 4; ++Mt) {
      #pragma unroll
      for (int r = 0; r < 4; ++r) {
        float v = acc[ntl][Mt][r] + bias;
        int t = t0 + Mt*16 + q*4 + r;
        y[((size_t)b*512 + t)*256 + ch] = f2bf(v);
        s0 += v; s1 += v*v;
      }
    }
    s0 += __shfl_xor(s0, 16); s0 += __shfl_xor(s0, 32);
    s1 += __shfl_xor(s1, 16); s1 += __shfl_xor(s1, 32);
    if (q == 0) { atomicAdd(&bnbuf[ch], s0); atomicAdd(&bnbuf[256 + ch], s1); }
  }
}

// ---------------------------------------------------------------------------
__global__ void k_bn(const uint16_t* __restrict__ gamma,
                     const uint16_t* __restrict__ beta,
                     float* __restrict__ bnbuf)
{
  int c = threadIdx.x;
  const float inv = 1.f / 131072.f;
  float mean = bnbuf[c] * inv;
  float var  = fmaxf(bnbuf[256 + c] * inv - mean*mean, 0.f);
  float sc   = bf2f(gamma[c]) * rsqrtf(var + 1e-5f);
  bnbuf[512 + c] = sc;
  bnbuf[768 + c] = bf2f(beta[c]) - mean * sc;
}

// ---------------------------------------------------------------------------
__global__ __launch_bounds__(256) void k_gx(
    const uint16_t* __restrict__ y, const float* __restrict__ bnbuf,
    const uint16_t* __restrict__ fragI, const uint16_t* __restrict__ bih,
    const uint16_t* __restrict__ bhh, uint16_t* __restrict__ gx, int tbase)
{
  __shared__ __align__(16) uint16_t aS[16384];
  int Mblk = blockIdx.x, Nblk = blockIdx.y;
  int tl = Mblk >> 2;
  int b0 = (Mblk & 3) * 64;
  int t = tbase + tl;
  int tid = threadIdx.x, lane = tid & 63, w = tid >> 6;
  int q = lane >> 4, c16 = lane & 15;

  for (int s = tid; s < 2048; s += 256) {
    int row = s >> 5, seg = s & 31;
    union { int4 i; uint16_t u[8]; } vv, oo;
    vv.i = *(const int4*)(y + ((size_t)(b0 + row)*512 + t)*256 + seg*8);
    #pragma unroll
    for (int j = 0; j < 8; ++j) {
      int ch = seg*8 + j;
      float f = bf2f(vv.u[j]) * bnbuf[512 + ch] + bnbuf[768 + ch];
      oo.u[j] = f2bf(fmaxf(f, 0.f));
    }
    int Mt = row >> 4, mL = row & 15, kt2 = seg >> 2, qq = seg & 3;
    *(int4*)(aS + ((Mt*8 + kt2)*64 + qq*16 + mL)*8) = oo.i;
  }
  __syncthreads();

  f32x4 acc[4][4];
  #pragma unroll
  for (int ntl = 0; ntl < 4; ++ntl) {
    int n = (Nblk*16 + w*4 + ntl)*16 + c16;
    float bias = bf2f(bih[n]) + bf2f(bhh[n]);
    #pragma unroll
    for (int Mt = 0; Mt < 4; ++Mt) acc[ntl][Mt] = (f32x4){bias,bias,bias,bias};
  }
  #pragma unroll
  for (int kt = 0; kt < 8; ++kt) {
    bf16x8 a[4];
    #pragma unroll
    for (int Mt = 0; Mt < 4; ++Mt)
      a[Mt] = ld_frag(aS + ((Mt*8 + kt)*64 + lane)*8);
    #pragma unroll
    for (int ntl = 0; ntl < 4; ++ntl) {
      int nt = Nblk*16 + w*4 + ntl;
      bf16x8 bf = ld_frag(fragI + ((size_t)(nt*8 + kt))*512 + lane*8);
      #pragma unroll
      for (int Mt = 0; Mt < 4; ++Mt)
        acc[ntl][Mt] = mfma16(a[Mt], bf, acc[ntl][Mt]);
    }
  }
  #pragma unroll
  for (int ntl = 0; ntl < 4; ++ntl) {
    int nt = Nblk*16 + w*4 + ntl;
    #pragma unroll
    for (int Mt = 0; Mt < 4; ++Mt) {
      int bg = (Mblk & 3)*4 + Mt;
      uint32_t lo = (uint32_t)f2bf(acc[ntl][Mt][0]) | ((uint32_t)f2bf(acc[ntl][Mt][1]) << 16);
      uint32_t hi = (uint32_t)f2bf(acc[ntl][Mt][2]) | ((uint32_t)f2bf(acc[ntl][Mt][3]) << 16);
      uint2 vv = {lo, hi};
      *(uint2*)(gx + ((size_t)(tl*16 + bg))*16384 + nt*256 + lane*4) = vv;
    }
  }
}

// ---------------------------------------------------------------------------
// k_lstm v2: 16 blocks x 512 threads. Block bg owns rows [16bg,16bg+16).
// Wave w owns units [32w,32w+32): gate tiles ntg={2w+p,16+2w+p,32+..,48+..}.
// Pipeline per step: prefetch gx(t+1) -> acc init from gx(t) -> issue kt4
// weight group -> ds_read all a-frags -> MFMA kt0..3 (resident) with rolling
// kt5/6/7 issues -> MFMA kt4..7 -> gates -> h to LDS dbuf -> barrier.
// ---------------------------------------------------------------------------
__global__ __launch_bounds__(512, 2) void k_lstm(
    const uint16_t* __restrict__ gx, const uint16_t* __restrict__ fragH,
    const int* __restrict__ lengths, uint16_t* __restrict__ wsH,
    float* __restrict__ wsC, float* __restrict__ hn,
    int tbase, int tcount, int last)
{
  __shared__ __align__(16) uint16_t aS[2 * 4096];
  int bg = blockIdx.x;
  int tid = threadIdx.x, lane = tid & 63, w = tid >> 6;
  int q = lane >> 4, c16 = lane & 15;

  ((int4*)aS)[tid] = ((const int4*)(wsH + bg*4096))[tid];  // h carry -> buf0

  int li[4];
  #pragma unroll
  for (int r = 0; r < 4; ++r) li[r] = lengths[bg*16 + q*4 + r];
  int Tmax = lengths[bg*16];                   // lengths sorted descending

  float cr[2][4], hr[2][4];
  #pragma unroll
  for (int p = 0; p < 2; ++p)
    #pragma unroll
    for (int r = 0; r < 4; ++r)
      cr[p][r] = wsC[(bg*16 + q*4 + r)*256 + w*32 + p*16 + c16];

  int ntg[8];
  bf16x8 breg[8][4];                           // w_hh kt0..3 resident
  #pragma unroll
  for (int gp = 0; gp < 8; ++gp) {
    ntg[gp] = (gp >> 1)*16 + 2*w + (gp & 1);
    #pragma unroll
    for (int kt = 0; kt < 4; ++kt)
      breg[gp][kt] = ld_frag(fragH + (ntg[gp]*8 + kt)*512 + lane*8);
  }

  // invariant per-lane offsets
  int hb = w*512 + q*32 + ((c16 >> 3) << 7) + (c16 & 7);   // h write/read base
  __syncthreads();

  #pragma unroll
  for (int p = 0; p < 2; ++p)
    #pragma unroll
    for (int r = 0; r < 4; ++r)
      hr[p][r] = bf2f(aS[hb + r*8 + p*256]);

  int cur = 0;
  int tEnd = min(tbase + tcount, Tmax);

  uint2 gcur[8], gnxt[8];
  if (tEnd > tbase) {
    const uint16_t* g0 = gx + (size_t)bg*16384 + lane*4;
    #pragma unroll
    for (int gp = 0; gp < 8; ++gp)
      gcur[gp] = *(const uint2*)(g0 + ntg[gp]*256);
  }

  for (int t = tbase; t < tEnd; ++t) {
    const uint16_t* Ar = aS + cur*4096;
    uint16_t* Aw = aS + (cur ^ 1)*4096;

    // 1. prefetch next step's gx (consumed next iteration)
    {
      int tn = (t + 1 < tEnd) ? (t + 1 - tbase) : (t - tbase);
      const uint16_t* gN = gx + ((size_t)(tn*16 + bg))*16384 + lane*4;
      #pragma unroll
      for (int gp = 0; gp < 8; ++gp)
        gnxt[gp] = *(const uint2*)(gN + ntg[gp]*256);
    }

    // 2. issue kt4 weight group early (L2)
    bf16x8 bbA[8], bbB[8];
    #pragma unroll
    for (int gp = 0; gp < 8; ++gp)
      bbA[gp] = ld_frag(fragH + (ntg[gp]*8 + 4)*512 + lane*8);

    // 3. acc init from gx(t)
    f32x4 acc[8];
    #pragma unroll
    for (int gp = 0; gp < 8; ++gp) {
      acc[gp][0] = bf2f((uint16_t)(gcur[gp].x & 0xffffu));
      acc[gp][1] = bf2f((uint16_t)(gcur[gp].x >> 16));
      acc[gp][2] = bf2f((uint16_t)(gcur[gp].y & 0xffffu));
      acc[gp][3] = bf2f((uint16_t)(gcur[gp].y >> 16));
    }

    // 4. a-frags (all 8 issued up front)
    bf16x8 a[8];
    #pragma unroll
    for (int kt = 0; kt < 8; ++kt)
      a[kt] = ld_frag(Ar + kt*512 + lane*8);

    // 5. MFMA kt0..1 (resident), issue kt5
    #pragma unroll
    for (int kt = 0; kt < 2; ++kt)
      #pragma unroll
      for (int gp = 0; gp < 8; ++gp)
        acc[gp] = mfma16(a[kt], breg[gp][kt], acc[gp]);
    #pragma unroll
    for (int gp = 0; gp < 8; ++gp)
      bbB[gp] = ld_frag(fragH + (ntg[gp]*8 + 5)*512 + lane*8);

    // 6. MFMA kt2..3 (resident)
    #pragma unroll
    for (int kt = 2; kt < 4; ++kt)
      #pragma unroll
      for (int gp = 0; gp < 8; ++gp)
        acc[gp] = mfma16(a[kt], breg[gp][kt], acc[gp]);

    // 7. MFMA kt4 (bbA), reissue bbA<-kt6
    #pragma unroll
    for (int gp = 0; gp < 8; ++gp)
      acc[gp] = mfma16(a[4], bbA[gp], acc[gp]);
    #pragma unroll
    for (int gp = 0; gp < 8; ++gp)
      bbA[gp] = ld_frag(fragH + (ntg[gp]*8 + 6)*512 + lane*8);

    // 8. MFMA kt5 (bbB), reissue bbB<-kt7
    #pragma unroll
    for (int gp = 0; gp < 8; ++gp)
      acc[gp] = mfma16(a[5], bbB[gp], acc[gp]);
    #pragma unroll
    for (int gp = 0; gp < 8; ++gp)
      bbB[gp] = ld_frag(fragH + (ntg[gp]*8 + 7)*512 + lane*8);

    // 9. MFMA kt6, kt7
    #pragma unroll
    for (int gp = 0; gp < 8; ++gp)
      acc[gp] = mfma16(a[6], bbA[gp], acc[gp]);
    #pragma unroll
    for (int gp = 0; gp < 8; ++gp)
      acc[gp] = mfma16(a[7], bbB[gp], acc[gp]);

    // 10. gates (gx already folded into acc)
    #pragma unroll
    for (int r = 0; r < 4; ++r) {
      bool upd = (t < li[r]);
      #pragma unroll
      for (int p = 0; p < 2; ++p) {
        float gi = acc[0 + p][r];
        float gf = acc[2 + p][r];
        float gg = acc[4 + p][r];
        float go = acc[6 + p][r];
        float cn = sigm(gf)*cr[p][r] + sigm(gi)*tanh_(gg);
        float hw = sigm(go)*tanh_(cn);
        cn = upd ? cn : cr[p][r];
        hw = upd ? hw : hr[p][r];
        cr[p][r] = cn; hr[p][r] = hw;
        Aw[hb + r*8 + p*256] = f2bf(hw);
      }
    }

    #pragma unroll
    for (int gp = 0; gp < 8; ++gp) gcur[gp] = gnxt[gp];
    __syncthreads();
    cur ^= 1;
  }

  ((int4*)(wsH + bg*4096))[tid] = ((const int4*)(aS + cur*4096))[tid];
  #pragma unroll
  for (int p = 0; p < 2; ++p)
    #pragma unroll
    for (int r = 0; r < 4; ++r)
      wsC[(bg*16 + q*4 + r)*256 + w*32 + p*16 + c16] = cr[p][r];

  if (last) {
    #pragma unroll
    for (int j = 0; j < 8; ++j)
      hn[(bg*16 + c16)*256 + w*32 + q*8 + j] =
          bf2f(aS[cur*4096 + w*512 + lane*8 + j]);
  }
}

// ---------------------------------------------------------------------------
__global__ __launch_bounds__(256) void k_attn(
    const uint16_t* __restrict__ y, const float* __restrict__ hn,
    const uint16_t* __restrict__ linw, const uint16_t* __restrict__ linb,
    void* __restrict__ outv, const int* __restrict__ flag)
{
  __shared__ float hnS[256];
  __shared__ float attnS[512];
  int b = blockIdx.x;
  int tid = threadIdx.x, lane = tid & 63, w = tid >> 6;
  int isb = *flag;
  hnS[tid] = hn[b*256 + tid];
  __syncthreads();
  for (int t = w; t < 512; t += 4) {
    uint2 d = *(const uint2*)(y + ((size_t)b*512 + t)*256 + lane*4);
    float s = bf2f((uint16_t)(d.x & 0xffffu)) * hnS[lane*4 + 0]
            + bf2f((uint16_t)(d.x >> 16))     * hnS[lane*4 + 1]
            + bf2f((uint16_t)(d.y & 0xffffu)) * hnS[lane*4 + 2]
            + bf2f((uint16_t)(d.y >> 16))     * hnS[lane*4 + 3];
    #pragma unroll
    for (int off = 32; off >= 1; off >>= 1) s += __shfl_xor(s, off);
    if (lane == 0) attnS[t] = s * 0.0625f;     // 1/sqrt(256)
  }
  __syncthreads();
  float acc = 0.f;
  #pragma unroll 4
  for (int t = 0; t < 512; ++t)
    acc += attnS[t] * bf2f(y[((size_t)b*512 + t)*256 + tid]);
  if (isb) ((uint16_t*)outv)[7936 + b*256 + tid] = f2bf(acc);
  else     ((float*)outv)[7936 + b*256 + tid] = acc;
  if (tid < 31) {
    float a2 = bf2f(linb[tid]);
    for (int k = 0; k < 256; ++k) a2 += hnS[k] * bf2f(linw[tid*256 + k]);
    if (isb) ((uint16_t*)outv)[b*31 + tid] = f2bf(a2);
    else     ((float*)outv)[b*31 + tid] = a2;
  }
}

// ---------------------------------------------------------------------------
extern "C" void kernel_launch(void* const* d_in, const int* in_sizes, int n_in,
                              void* d_out, int out_size, void* d_ws, size_t ws_size,
                              hipStream_t stream)
{
  (void)in_sizes; (void)out_size;
  if (n_in < 15) return;
  const int* x   = (const int*)d_in[0];
  const int* len = (const int*)d_in[1];

  uint8_t* p = (uint8_t*)d_ws;
  auto take = [&](size_t n){ uint8_t* r = p; p += (n + 255) & ~(size_t)255; return r; };
  int*      flag  = (int*)take(256);
  uint16_t* c1bC  = (uint16_t*)take(256);
  uint16_t* c2bC  = (uint16_t*)take(256);
  uint16_t* bngC  = (uint16_t*)take(512);
  uint16_t* bnbC  = (uint16_t*)take(512);
  uint16_t* bihC  = (uint16_t*)take(2048);
  uint16_t* bhhC  = (uint16_t*)take(2048);
  uint16_t* linwC = (uint16_t*)take(15872);
  uint16_t* linbC = (uint16_t*)take(64);
  uint16_t* fragC = (uint16_t*)take(327680);
  uint16_t* fragI = (uint16_t*)take(524288);
  uint16_t* fragH = (uint16_t*)take(524288);
  float*    bnbuf = (float*)take(4096);
  uint16_t* wsH   = (uint16_t*)take(131072);
  float*    wsC   = (float*)take(262144);
  float*    hnbuf = (float*)take(262144);
  uint16_t* y     = (uint16_t*)take(67108864ull);
  uint16_t* gxb   = (uint16_t*)take(67108864ull);
  if ((size_t)(p - (uint8_t*)d_ws) > ws_size) return;

  // big converted tensors live inside gxb (dead before k_gx first writes it)
  uint16_t* etabC = gxb;
  uint16_t* c1wC  = (uint16_t*)((uint8_t*)gxb + 16u*1024*1024);
  uint16_t* c2wC  = (uint16_t*)((uint8_t*)gxb + 17u*1024*1024);
  uint16_t* wihC  = (uint16_t*)((uint8_t*)gxb + 18u*1024*1024);
  uint16_t* whhC  = (uint16_t*)((uint8_t*)gxb + 19u*1024*1024);

  k_sniff<<<1, 256, 0, stream>>>((const uint32_t*)d_in[2], flag);

  CvtArgs A;
  int c0 = 0;
  auto put = [&](int i, const void* s, uint16_t* d, int n){
    A.a[i].s = s; A.a[i].d = d; A.a[i].n = n; A.a[i].c0 = c0;
    c0 += (n + 4095) / 4096;
  };
  put(0,  d_in[2],  etabC, 6400000);
  put(1,  d_in[3],  c1wC,  49152);
  put(2,  d_in[4],  c1bC,  128);
  put(3,  d_in[5],  c2wC,  81920);
  put(4,  d_in[6],  c2bC,  128);
  put(5,  d_in[7],  bngC,  256);
  put(6,  d_in[8],  bnbC,  256);
  put(7,  d_in[9],  wihC,  262144);
  put(8,  d_in[10], whhC,  262144);
  put(9,  d_in[11], bihC,  1024);
  put(10, d_in[12], bhhC,  1024);
  put(11, d_in[13], linwC, 7936);
  put(12, d_in[14], linbC, 31);
  k_cvt<<<c0, 256, 0, stream>>>(A, flag);

  k_prep<<<512, 256, 0, stream>>>(c1wC, c2wC, wihC, whhC, fragC, fragI, fragH,
                                  bnbuf, wsH, wsC);
  k_conv<<<2048, 256, 0, stream>>>(x, etabC, fragC, c1bC, c2bC, y, bnbuf);
  k_bn<<<1, 256, 0, stream>>>(bngC, bnbC, bnbuf);
  for (int c = 0; c < 4; ++c) {
    k_gx<<<dim3(512, 4), 256, 0, stream>>>(y, bnbuf, fragI, bihC, bhhC, gxb, c*128);
    k_lstm<<<16, 512, 0, stream>>>(gxb, fragH, len, wsH, wsC, hnbuf,
                                   c*128, 128, (c == 3) ? 1 : 0);
  }
  k_attn<<<256, 256, 0, stream>>>(y, hnbuf, linwC, linbC, d_out, flag);
}